// Round 9
// baseline (593.478 us; speedup 1.0000x reference)
//
#include <hip/hip_runtime.h>
#include <hip/hip_bf16.h>
#include <stdint.h>

// GCN 3-layer + head, bf16 data path, fp32 accumulate everywhere.
// Identity: Â(XW) = (ÂX)W; aggregate on the narrower side.
// Scaled-space: store ṽ = dinv⊙v (bf16) -> gather loop is a pure row-sum.
// R9: CSR construction via 2-level bucket binning (bucket = dst>>8):
//   bin:    append edges to per-bucket regions (cursor atomics -> sequential
//           line-filling writes, no 64B-line amplification)
//   bhist:  per-bucket degree count in LDS -> coalesced cnt writes
//   bfill:  per-bucket scatter; csr dst span ~8KB -> L2 dirty-merge
// Replaces hist_kernel (800K random global atomics) + fill_kernel
// (58.7MB amplified random writes, 57us).

typedef __attribute__((ext_vector_type(8))) short bf16x8;
typedef __attribute__((ext_vector_type(16))) float f32x16;

__device__ __forceinline__ float bf_lo(uint32_t u) {
    union { uint32_t i; float f; } v; v.i = u << 16; return v.f;
}
__device__ __forceinline__ float bf_hi(uint32_t u) {
    union { uint32_t i; float f; } v; v.i = u & 0xffff0000u; return v.f;
}
__device__ __forceinline__ float bf_s(uint16_t h) {
    union { uint32_t i; float f; } v; v.i = ((uint32_t)h) << 16; return v.f;
}
__device__ __forceinline__ uint16_t f2bf(float f) {   // RNE
    union { float f; uint32_t i; } v; v.f = f;
    uint32_t r = v.i + 0x7fffu + ((v.i >> 16) & 1u);
    return (uint16_t)(r >> 16);
}
__device__ __forceinline__ uint32_t packbf(float a, float b) {
    return (uint32_t)f2bf(a) | ((uint32_t)f2bf(b) << 16);
}

constexpr int BCAP = 4096;   // edges per bucket region (mean ~2048, sd ~45)

// ---------------- bucket binning ----------------
__global__ __launch_bounds__(256) void bin_kernel(const int* __restrict__ src,
                                                  const int* __restrict__ dst,
                                                  int* __restrict__ gcur,
                                                  int2* __restrict__ ebuf, int E) {
    int e = blockIdx.x * 256 + threadIdx.x;
    if (e < E) {
        int d = dst[e];
        int b = d >> 8;
        int slot = atomicAdd(&gcur[b], 1);
        if (slot < BCAP) ebuf[b * BCAP + slot] = make_int2(src[e], d);
    }
}

// one block per bucket: degree histogram in LDS, coalesced cnt write
__global__ __launch_bounds__(256) void bucket_hist(const int* __restrict__ gcur,
                                                   const int2* __restrict__ ebuf,
                                                   int* __restrict__ cnt, int N) {
    int b = blockIdx.x, t = threadIdx.x;
    __shared__ int h[256];
    h[t] = 0;
    __syncthreads();
    int cb = gcur[b]; if (cb > BCAP) cb = BCAP;
    for (int i = t; i < cb; i += 256)
        atomicAdd(&h[ebuf[b * BCAP + i].y & 255], 1);
    __syncthreads();
    int node = b * 256 + t;
    if (node < N) cnt[node] = h[t];
}

// one block per bucket: scatter src into csr (dst span ~8KB -> L2 merge)
__global__ __launch_bounds__(256) void bucket_fill(const int* __restrict__ gcur,
                                                   const int2* __restrict__ ebuf,
                                                   const int* __restrict__ row_ptr,
                                                   int* __restrict__ csr_src, int N) {
    int b = blockIdx.x, t = threadIdx.x;
    __shared__ int cur[256];
    cur[t] = 0;
    __syncthreads();
    int cb = gcur[b]; if (cb > BCAP) cb = BCAP;
    for (int i = t; i < cb; i += 256) {
        int2 p = ebuf[b * BCAP + i];
        int local = atomicAdd(&cur[p.y & 255], 1);
        csr_src[row_ptr[p.y] + local] = p.x;
    }
}

__global__ __launch_bounds__(256) void dinv_kernel(const int* __restrict__ cnt,
                                                   float* __restrict__ dinv, int N) {
    int i = blockIdx.x * 256 + threadIdx.x;
    if (i < N) dinv[i] = rsqrtf((float)cnt[i] + 1.0f);
}

// 3-phase scan (98 blocks of 1024 elems).
__global__ __launch_bounds__(256) void scan_blk(const int* __restrict__ cnt,
                                                int* __restrict__ row_ptr,
                                                int* __restrict__ bsum, int N) {
    int b = blockIdx.x, t = threadIdx.x;
    int base = b * 1024 + t * 4;
    int v0 = 0, v1 = 0, v2 = 0, v3 = 0;
    if (base + 3 < N) {
        int4 q = *(const int4*)(cnt + base);
        v0 = q.x; v1 = q.y; v2 = q.z; v3 = q.w;
    } else if (base < N) {
        v0 = cnt[base];
        if (base + 1 < N) v1 = cnt[base + 1];
        if (base + 2 < N) v2 = cnt[base + 2];
    }
    int tsum = v0 + v1 + v2 + v3;
    __shared__ int ps[256];
    ps[t] = tsum;
    __syncthreads();
    for (int off = 1; off < 256; off <<= 1) {
        int x = (t >= off) ? ps[t - off] : 0;
        __syncthreads();
        ps[t] += x;
        __syncthreads();
    }
    int ex = (t == 0) ? 0 : ps[t - 1];
    if (t == 255) bsum[b] = ps[255];
    if (base + 3 < N) {
        int4 w; w.x = ex; w.y = ex + v0; w.z = ex + v0 + v1; w.w = ex + v0 + v1 + v2;
        *(int4*)(row_ptr + base) = w;
    } else if (base < N) {
        row_ptr[base] = ex;
        if (base + 1 < N) row_ptr[base + 1] = ex + v0;
        if (base + 2 < N) row_ptr[base + 2] = ex + v0 + v1;
    }
}

__global__ __launch_bounds__(128) void scan_tops(int* __restrict__ bsum, int NB) {
    __shared__ int ps[128];
    int t = threadIdx.x;
    int v = (t < NB) ? bsum[t] : 0;
    ps[t] = v;
    __syncthreads();
    for (int off = 1; off < 128; off <<= 1) {
        int x = (t >= off) ? ps[t - off] : 0;
        __syncthreads();
        ps[t] += x;
        __syncthreads();
    }
    if (t < NB) bsum[t] = (t == 0) ? 0 : ps[t - 1];
}

__global__ __launch_bounds__(256) void scan_add(int* __restrict__ row_ptr,
                                                const int* __restrict__ bsum,
                                                int N, int E) {
    int b = blockIdx.x, t = threadIdx.x;
    int base = b * 1024 + t * 4;
    int off = bsum[b];
    if (base + 3 < N) {
        int4 q = *(int4*)(row_ptr + base);
        q.x += off; q.y += off; q.z += off; q.w += off;
        *(int4*)(row_ptr + base) = q;
    } else {
        for (int i = 0; i < 4; ++i)
            if (base + i < N) row_ptr[base + i] += off;
    }
    if (b == 0 && t == 0) row_ptr[N] = E;
}

// ---------------- wprep: W (fp32, [k][m]) -> Wt (bf16, [m][k]) ----------------
template <int K, int M>
__device__ __forceinline__ void wprep_one(const float* __restrict__ W,
                                          uint16_t* __restrict__ Wt, int j) {
    int m = j / K, k = j % K;
    Wt[j] = f2bf(W[k * M + m]);
}
__global__ __launch_bounds__(256) void wprep(const float* __restrict__ W1,
                                             const float* __restrict__ W2,
                                             const float* __restrict__ W3,
                                             uint16_t* __restrict__ Wt1,
                                             uint16_t* __restrict__ Wt2,
                                             uint16_t* __restrict__ Wt3) {
    int i = blockIdx.x * 256 + threadIdx.x;
    if (i < 32768) {
        wprep_one<128, 256>(W1, Wt1, i);          // W1: 128x256
    } else if (i < 65536) {
        wprep_one<256, 128>(W2, Wt2, i - 32768);  // W2: 256x128
    } else if (i < 73728) {
        wprep_one<128, 64>(W3, Wt3, i - 65536);   // W3: 128x64
    }
}

// ---------------- P0: U0 = bf16(dinv ⊙ x) ----------------
__global__ __launch_bounds__(256) void scale_cvt(const float* __restrict__ x,
                                                 const float* __restrict__ dinv,
                                                 uint32_t* __restrict__ U, long total) {
    long i = (long)blockIdx.x * 256 + threadIdx.x;
    if (i >= total) return;
    int row = (int)(i >> 6);
    float2 v = ((const float2*)x)[i];
    float d = dinv[row];
    U[i] = packbf(d * v.x, d * v.y);
}

// ---------------- aggregation, 128 channels (wave per node) ----------------
template <bool BIAS_RELU>
__global__ __launch_bounds__(256) void agg128(const uint32_t* __restrict__ U,
                                              const float* __restrict__ dinv,
                                              const int* __restrict__ row_ptr,
                                              const int* __restrict__ csr_src,
                                              const float* __restrict__ bias,
                                              uint32_t* __restrict__ Out, int N) {
    int wave = threadIdx.x >> 6, lane = threadIdx.x & 63;
    int n = blockIdx.x * 4 + wave;
    if (n >= N) return;
    uint32_t u = U[(long)n * 64 + lane];
    float s0 = bf_lo(u), s1 = bf_hi(u);
    int e0 = row_ptr[n], e1 = row_ptr[n + 1];
    for (int e = e0; e < e1; e += 8) {
        int idx[8];
        uint32_t uu[8];
#pragma unroll
        for (int j = 0; j < 8; ++j) {
            int ee = e + j; if (ee > e1 - 1) ee = e1 - 1;
            idx[j] = csr_src[ee];
        }
#pragma unroll
        for (int j = 0; j < 8; ++j) uu[j] = U[(long)idx[j] * 64 + lane];
#pragma unroll
        for (int j = 0; j < 8; ++j) {
            float m = (e + j < e1) ? 1.f : 0.f;
            s0 += m * bf_lo(uu[j]);
            s1 += m * bf_hi(uu[j]);
        }
    }
    float d = dinv[n];
    float r0 = d * s0, r1 = d * s1;
    if constexpr (BIAS_RELU) {
        r0 = fmaxf(r0 + bias[2 * lane], 0.f);
        r1 = fmaxf(r1 + bias[2 * lane + 1], 0.f);
    }
    Out[(long)n * 64 + lane] = packbf(r0, r1);
}

// ---------------- agg 64 channels + bias/relu + linear head ----------------
__global__ __launch_bounds__(256) void agg64_head(const uint16_t* __restrict__ U,
                                                  const float* __restrict__ dinv,
                                                  const int* __restrict__ row_ptr,
                                                  const int* __restrict__ csr_src,
                                                  const float* __restrict__ b3,
                                                  const float* __restrict__ Wl,
                                                  const float* __restrict__ bl,
                                                  float* __restrict__ out, int N) {
    int wave = threadIdx.x >> 6, lane = threadIdx.x & 63;
    int n = blockIdx.x * 4 + wave;
    if (n >= N) return;
    float s = bf_s(U[(long)n * 64 + lane]);
    int e0 = row_ptr[n], e1 = row_ptr[n + 1];
    for (int e = e0; e < e1; e += 8) {
        int idx[8];
        uint16_t uu[8];
#pragma unroll
        for (int j = 0; j < 8; ++j) {
            int ee = e + j; if (ee > e1 - 1) ee = e1 - 1;
            idx[j] = csr_src[ee];
        }
#pragma unroll
        for (int j = 0; j < 8; ++j) uu[j] = U[(long)idx[j] * 64 + lane];
#pragma unroll
        for (int j = 0; j < 8; ++j) {
            float m = (e + j < e1) ? 1.f : 0.f;
            s += m * bf_s(uu[j]);
        }
    }
    float h = fmaxf(dinv[n] * s + b3[lane], 0.f);
    float v = h * Wl[lane];
#pragma unroll
    for (int off = 32; off; off >>= 1) v += __shfl_xor(v, off);
    if (lane == 0) out[n] = v + bl[0];
}

// ---------------- FUSED gemm1+gemm2 (transposed MFMA, spill-free) ----------------
__global__ __launch_bounds__(256, 2) void gemm_fused12(const uint16_t* __restrict__ A,
                                                       const uint16_t* __restrict__ Wt1,
                                                       const float* __restrict__ b1,
                                                       const uint16_t* __restrict__ Wt2,
                                                       const float* __restrict__ dinv,
                                                       uint16_t* __restrict__ Y, int N) {
    constexpr int SD = 136;            // 128 + 8 shorts; 68 dw = 4 mod 32 -> conflict-free
    __shared__ short wl[128 * SD];     // 34,816 B

    int t = threadIdx.x;
    int wave = t >> 6, lane = t & 63;
    int l31 = lane & 31, lhi = lane >> 5;
    long row0 = (long)blockIdx.x * 128 + wave * 32;

    bf16x8 afrag[8];
    {
        long arow = row0 + l31; if (arow > N - 1) arow = N - 1;
        const uint16_t* ap = A + arow * 128 + lhi * 8;
#pragma unroll
        for (int s = 0; s < 8; ++s)
            afrag[s] = *(const bf16x8*)(ap + s * 16);
    }

    int srow = t >> 4, scol = (t & 15) * 8;
    uint32_t pk[32][2];

    // ---- phase 1: two c-halves, one 64-AGPR accumulator ----
#pragma unroll
    for (int h = 0; h < 2; ++h) {
#pragma unroll
        for (int i = 0; i < 8; ++i) {
            int r = srow + 16 * i;
            *(bf16x8*)(wl + r * SD + scol) =
                *(const bf16x8*)(Wt1 + (long)(h * 128 + r) * 128 + scol);
        }
        __syncthreads();
        f32x16 acc[4];
#pragma unroll
        for (int c = 0; c < 4; ++c)
#pragma unroll
            for (int r = 0; r < 16; ++r) acc[c][r] = 0.f;
#pragma unroll
        for (int s = 0; s < 8; ++s) {
            const short* bp = wl + l31 * SD + s * 16 + lhi * 8;
#pragma unroll
            for (int c = 0; c < 4; ++c) {
                bf16x8 wfrag = *(const bf16x8*)(bp + c * 32 * SD);
                acc[c] = __builtin_amdgcn_mfma_f32_32x32x16_bf16(
                    wfrag, afrag[s], acc[c], 0, 0, 0);
            }
        }
        __syncthreads();
#pragma unroll
        for (int c = 0; c < 4; ++c) {
#pragma unroll
            for (int g = 0; g < 4; ++g) {
                int m0 = (4 * h + c) * 32 + g * 8 + 4 * lhi;
                float4 bv = *(const float4*)(b1 + m0);
                float v0 = fmaxf(acc[c][g * 4 + 0] + bv.x, 0.f);
                float v1 = fmaxf(acc[c][g * 4 + 1] + bv.y, 0.f);
                float v2 = fmaxf(acc[c][g * 4 + 2] + bv.z, 0.f);
                float v3 = fmaxf(acc[c][g * 4 + 3] + bv.w, 0.f);
                pk[(4 * h + c) * 4 + g][0] = packbf(v0, v1);
                pk[(4 * h + c) * 4 + g][1] = packbf(v2, v3);
            }
        }
    }

    // ---- phase 2: K2=256 in two chunks of 128; M2=128 ----
    f32x16 acc2[4];
#pragma unroll
    for (int c = 0; c < 4; ++c)
#pragma unroll
        for (int r = 0; r < 16; ++r) acc2[c][r] = 0.f;

#pragma unroll
    for (int kq = 0; kq < 2; ++kq) {
        const int kc0 = kq * 128;
#pragma unroll
        for (int i = 0; i < 8; ++i) {
            int r = srow + 16 * i;
            *(bf16x8*)(wl + r * SD + scol) =
                *(const bf16x8*)(Wt2 + (long)r * 256 + kc0 + scol);
        }
        __syncthreads();
#pragma unroll
        for (int sl = 0; sl < 8; ++sl) {
            const int s = kc0 / 16 + sl;
            uint32_t send0 = lhi ? pk[2 * s][0] : pk[2 * s + 1][0];
            uint32_t send1 = lhi ? pk[2 * s][1] : pk[2 * s + 1][1];
            uint32_t rcv0 = __shfl_xor(send0, 32);
            uint32_t rcv1 = __shfl_xor(send1, 32);
            uint32_t lc0 = lhi ? pk[2 * s + 1][0] : pk[2 * s][0];
            uint32_t lc1 = lhi ? pk[2 * s + 1][1] : pk[2 * s][1];
            union { uint32_t u[4]; bf16x8 v; } hf;
            hf.u[0] = lhi ? rcv0 : lc0;
            hf.u[1] = lhi ? rcv1 : lc1;
            hf.u[2] = lhi ? lc0 : rcv0;
            hf.u[3] = lhi ? lc1 : rcv1;
            const short* bp = wl + l31 * SD + sl * 16 + lhi * 8;
#pragma unroll
            for (int c = 0; c < 4; ++c) {
                bf16x8 wfrag = *(const bf16x8*)(bp + c * 32 * SD);
                acc2[c] = __builtin_amdgcn_mfma_f32_32x32x16_bf16(
                    wfrag, hf.v, acc2[c], 0, 0, 0);
            }
        }
        __syncthreads();
    }

    long node = row0 + l31;
    bool ok = node < N;
    long nclamp = ok ? node : (N - 1);
    float dn = dinv[nclamp];
    uint16_t* yp = Y + nclamp * 128;
#pragma unroll
    for (int c = 0; c < 4; ++c) {
#pragma unroll
        for (int g = 0; g < 4; ++g) {
            int m0 = c * 32 + g * 8 + 4 * lhi;
            float v0 = acc2[c][g * 4 + 0] * dn;
            float v1 = acc2[c][g * 4 + 1] * dn;
            float v2 = acc2[c][g * 4 + 2] * dn;
            float v3 = acc2[c][g * 4 + 3] * dn;
            if (ok) {
                uint2 pko; pko.x = packbf(v0, v1); pko.y = packbf(v2, v3);
                *(uint2*)(yp + m0) = pko;
            }
        }
    }
}

// ---------------- MFMA GEMM (transposed), for layer 3 ----------------
template <int K, int M, bool BIAS_RELU, bool SCALE_OUT>
__global__ __launch_bounds__(256, 2) void gemm_mfma(const uint16_t* __restrict__ A,
                                                    const uint16_t* __restrict__ Wt,
                                                    const float* __restrict__ bias,
                                                    const float* __restrict__ dinv,
                                                    uint16_t* __restrict__ Y, int N) {
    constexpr int NT = M / 32;
    constexpr int NK = K / 16;
    constexpr int KC = 64;
    constexpr int SD = KC + 8;
    constexpr int CPR = KC / 8;
    __shared__ short wl[M * SD];

    int t = threadIdx.x;
    int wave = t >> 6, lane = t & 63;
    int l31 = lane & 31, lhi = lane >> 5;
    long row0 = (long)blockIdx.x * 128 + wave * 32;

    bf16x8 afrag[NK];
    {
        long arow = row0 + l31; if (arow > N - 1) arow = N - 1;
        const uint16_t* ap = A + arow * K + lhi * 8;
#pragma unroll
        for (int s = 0; s < NK; ++s)
            afrag[s] = *(const bf16x8*)(ap + s * 16);
    }

    f32x16 acc[NT];
#pragma unroll
    for (int c = 0; c < NT; ++c)
#pragma unroll
        for (int r = 0; r < 16; ++r) acc[c][r] = 0.f;

    int r0 = t / CPR, cc8 = (t % CPR) * 8;
    for (int kc0 = 0; kc0 < K; kc0 += KC) {
#pragma unroll
        for (int r = r0; r < M; r += 256 / CPR)
            *(bf16x8*)(wl + r * SD + cc8) = *(const bf16x8*)(Wt + (long)r * K + kc0 + cc8);
        __syncthreads();
#pragma unroll
        for (int s = 0; s < KC / 16; ++s) {
            const short* bp = wl + l31 * SD + s * 16 + lhi * 8;
#pragma unroll
            for (int c = 0; c < NT; ++c) {
                bf16x8 wfrag = *(const bf16x8*)(bp + c * 32 * SD);
                acc[c] = __builtin_amdgcn_mfma_f32_32x32x16_bf16(
                    wfrag, afrag[kc0 / 16 + s], acc[c], 0, 0, 0);
            }
        }
        __syncthreads();
    }

    long node = row0 + l31;
    bool ok = node < N;
    long nclamp = ok ? node : (N - 1);
    float dn = SCALE_OUT ? dinv[nclamp] : 1.f;
    uint16_t* yp = Y + nclamp * M;
#pragma unroll
    for (int c = 0; c < NT; ++c) {
#pragma unroll
        for (int g = 0; g < 4; ++g) {
            int m0 = c * 32 + g * 8 + 4 * lhi;
            float v[4];
#pragma unroll
            for (int j = 0; j < 4; ++j) {
                float x = acc[c][g * 4 + j];
                if constexpr (BIAS_RELU) x = fmaxf(x + bias[m0 + j], 0.f);
                if constexpr (SCALE_OUT) x *= dn;
                v[j] = x;
            }
            if (ok) {
                uint2 pk; pk.x = packbf(v[0], v[1]); pk.y = packbf(v[2], v[3]);
                *(uint2*)(yp + m0) = pk;
            }
        }
    }
}

extern "C" void kernel_launch(void* const* d_in, const int* in_sizes, int n_in,
                              void* d_out, int out_size, void* d_ws, size_t ws_size,
                              hipStream_t stream) {
    const float* x  = (const float*)d_in[0];
    const int* edge = (const int*)d_in[1];
    const float* W1 = (const float*)d_in[2];
    const float* b1 = (const float*)d_in[3];
    const float* W2 = (const float*)d_in[4];
    const float* b2 = (const float*)d_in[5];
    const float* W3 = (const float*)d_in[6];
    const float* b3 = (const float*)d_in[7];
    const float* Wl = (const float*)d_in[8];
    const float* bl = (const float*)d_in[9];
    float* out = (float*)d_out;

    int N = in_sizes[0] / 128;   // 100000
    int E = in_sizes[1] / 2;     // 800000
    const int* src = edge;
    const int* dst = edge + E;

    char* ws = (char*)d_ws;
    size_t off = 0;
    auto alloc = [&](size_t bytes) {
        void* p = ws + off;
        off += (bytes + 255) & ~(size_t)255;
        return p;
    };
    int NBK = (N + 255) / 256;   // 391 buckets

    int*      cnt     = (int*)     alloc((size_t)N * 4);
    int*      row_ptr = (int*)     alloc((size_t)(N + 1) * 4);
    float*    dinv    = (float*)   alloc((size_t)N * 4);
    int*      csr_src = (int*)     alloc((size_t)E * 4);
    int*      bsum    = (int*)     alloc(128 * 4);
    int*      gcur    = (int*)     alloc((size_t)NBK * 4);
    int2*     ebuf    = (int2*)    alloc((size_t)NBK * BCAP * 8);
    uint16_t* Wt1     = (uint16_t*)alloc(256 * 128 * 2);
    uint16_t* Wt2     = (uint16_t*)alloc(128 * 256 * 2);
    uint16_t* Wt3     = (uint16_t*)alloc(64 * 128 * 2);
    uint32_t* B_a     = (uint32_t*)alloc((size_t)N * 64 * 4);    // 128ch bf16
    uint32_t* B_b     = (uint32_t*)alloc((size_t)N * 64 * 4);    // 128ch bf16
    (void)ws_size; (void)n_in; (void)out_size;

    int NB = (N + 1023) / 1024;   // 98

    // graph preprocessing (rebuilt every launch; ws is re-poisoned)
    hipMemsetAsync(gcur, 0, (size_t)NBK * 4, stream);
    bin_kernel<<<(E + 255) / 256, 256, 0, stream>>>(src, dst, gcur, ebuf, E);
    bucket_hist<<<NBK, 256, 0, stream>>>(gcur, ebuf, cnt, N);
    dinv_kernel<<<(N + 255) / 256, 256, 0, stream>>>(cnt, dinv, N);
    scan_blk<<<NB, 256, 0, stream>>>(cnt, row_ptr, bsum, N);
    scan_tops<<<1, 128, 0, stream>>>(bsum, NB);
    scan_add<<<NB, 256, 0, stream>>>(row_ptr, bsum, N, E);
    bucket_fill<<<NBK, 256, 0, stream>>>(gcur, ebuf, row_ptr, csr_src, N);
    wprep<<<288, 256, 0, stream>>>(W1, W2, W3, Wt1, Wt2, Wt3);

    // P0
    scale_cvt<<<(int)(((long)N * 64 + 255) / 256), 256, 0, stream>>>(x, dinv, B_a, (long)N * 64);
    // layer 1 aggregation
    agg128<false><<<(N + 3) / 4, 256, 0, stream>>>(B_a, dinv, row_ptr, csr_src, nullptr, B_b, N);
    // fused: U2 = dinv ⊙ (relu(A1@W1+b1) @ W2)
    gemm_fused12<<<(N + 127) / 128, 256, 0, stream>>>(
        (const uint16_t*)B_b, Wt1, b1, Wt2, dinv, (uint16_t*)B_a, N);
    // layer 2 aggregation
    agg128<true><<<(N + 3) / 4, 256, 0, stream>>>(B_a, dinv, row_ptr, csr_src, b2, B_b, N);
    // layer 3 GEMM
    gemm_mfma<128, 64, false, true><<<(N + 127) / 128, 256, 0, stream>>>(
        (const uint16_t*)B_b, Wt3, nullptr, dinv, (uint16_t*)B_a, N);
    // agg + head
    agg64_head<<<(N + 3) / 4, 256, 0, stream>>>(
        (const uint16_t*)B_a, dinv, row_ptr, csr_src, b3, Wl, bl, out, N);
}